// Round 1
// baseline (931.877 us; speedup 1.0000x reference)
//
#include <hip/hip_runtime.h>
#include <hip/hip_bf16.h>

// NeRF ray-marching renderer, MI355X.
// rays: 262144, steps: 128, grid: 128^3, sigma (f32) + rgb (f32x3) trilerp,
// alpha compositing with early termination, bg blend, clip to [0,1].

constexpr int   kG     = 128;
constexpr int   kG3    = kG * kG * kG;
constexpr int   kSteps = 128;
constexpr int   kNRays = 262144;
constexpr float kBminX = -1.0f, kBminY = -0.5f, kBminZ = -1.0f;
constexpr float kBmaxX =  1.0f, kBmaxY =  0.5f, kBmaxZ =  1.0f;
constexpr float kMinNear = 0.05f;
constexpr float kDenTh   = 0.01f;
constexpr float kTTh     = 1e-4f;

// Repack sigma (8 MB) + rgb (24 MB) into interleaved float4 voxels (32 MB)
// so each trilerp corner is ONE global_load_dwordx4 on one cache line.
__global__ __launch_bounds__(256) void repack_k(
    const float* __restrict__ sig, const float* __restrict__ rgb,
    float4* __restrict__ out)
{
    int i = blockIdx.x * 256 + threadIdx.x;
    if (i >= kG3) return;
    out[i] = make_float4(sig[i], rgb[3 * i + 0], rgb[3 * i + 1], rgb[3 * i + 2]);
}

template <int INTERLEAVED>
__global__ __launch_bounds__(256) void render_k(
    const float* __restrict__ rays_o, const float* __restrict__ rays_d,
    const float4* __restrict__ g4,
    const float* __restrict__ sgrid, const float* __restrict__ cgrid,
    const float* __restrict__ bg, float* __restrict__ out)
{
    int i = blockIdx.x * 256 + threadIdx.x;
    if (i >= kNRays) return;

    float ox = rays_o[3 * i + 0], oy = rays_o[3 * i + 1], oz = rays_o[3 * i + 2];
    float dx = rays_d[3 * i + 0], dy = rays_d[3 * i + 1], dz = rays_d[3 * i + 2];

    // AABB slab test (matches reference's safe_d handling)
    float sdx = (fabsf(dx) < 1e-9f) ? 1e-9f : dx;
    float sdy = (fabsf(dy) < 1e-9f) ? 1e-9f : dy;
    float sdz = (fabsf(dz) < 1e-9f) ? 1e-9f : dz;
    float t1x = (kBminX - ox) / sdx, t2x = (kBmaxX - ox) / sdx;
    float t1y = (kBminY - oy) / sdy, t2y = (kBmaxY - oy) / sdy;
    float t1z = (kBminZ - oz) / sdz, t2z = (kBmaxZ - oz) / sdz;
    float near_ = fmaxf(fmaxf(fminf(t1x, t2x), fminf(t1y, t2y)), fminf(t1z, t2z));
    float far_  = fminf(fminf(fmaxf(t1x, t2x), fmaxf(t1y, t2y)), fmaxf(t1z, t2z));
    near_ = fmaxf(near_, kMinNear);
    far_  = fmaxf(far_, near_ + 1e-6f);
    float dt = (far_ - near_) * (1.0f / (float)kSteps);

    const float sxs = (float)(kG - 1) / (kBmaxX - kBminX);
    const float sys = (float)(kG - 1) / (kBmaxY - kBminY);
    const float szs = (float)(kG - 1) / (kBmaxZ - kBminZ);

    float T = 1.0f, wsum = 0.0f;
    float accr = 0.0f, accg = 0.0f, accb = 0.0f;

    for (int s = 0; s < kSteps; ++s) {
        float t  = fmaf((float)s + 0.5f, dt, near_);
        float px = fmaf(t, dx, ox);
        float py = fmaf(t, dy, oy);
        float pz = fmaf(t, dz, oz);

        float ux = fminf(fmaxf((px - kBminX) * sxs, 0.0f), (float)(kG - 1));
        float uy = fminf(fmaxf((py - kBminY) * sys, 0.0f), (float)(kG - 1));
        float uz = fminf(fmaxf((pz - kBminZ) * szs, 0.0f), (float)(kG - 1));
        float u0x = fminf(floorf(ux), (float)(kG - 2));
        float u0y = fminf(floorf(uy), (float)(kG - 2));
        float u0z = fminf(floorf(uz), (float)(kG - 2));
        float fx = ux - u0x, fy = uy - u0y, fz = uz - u0z;
        int ix = (int)u0x, iy = (int)u0y, iz = (int)u0z;
        int base = (ix << 14) + (iy << 7) + iz;

        float w0x = 1.0f - fx, w0y = 1.0f - fy, w0z = 1.0f - fz;
        float wa = w0x * w0y * w0z;   // 000
        float wb = w0x * w0y * fz;    // 001
        float wc = w0x * fy  * w0z;   // 010
        float wd = w0x * fy  * fz;    // 011
        float we = fx  * w0y * w0z;   // 100
        float wf = fx  * w0y * fz;    // 101
        float wg = fx  * fy  * w0z;   // 110
        float wh = fx  * fy  * fz;    // 111

        float sv, rv, gv, bv;
        if (INTERLEAVED) {
            float4 c000 = g4[base];
            float4 c001 = g4[base + 1];
            float4 c010 = g4[base + kG];
            float4 c011 = g4[base + kG + 1];
            float4 c100 = g4[base + kG * kG];
            float4 c101 = g4[base + kG * kG + 1];
            float4 c110 = g4[base + kG * kG + kG];
            float4 c111 = g4[base + kG * kG + kG + 1];
            sv = wa * c000.x + wb * c001.x + wc * c010.x + wd * c011.x
               + we * c100.x + wf * c101.x + wg * c110.x + wh * c111.x;
            rv = wa * c000.y + wb * c001.y + wc * c010.y + wd * c011.y
               + we * c100.y + wf * c101.y + wg * c110.y + wh * c111.y;
            gv = wa * c000.z + wb * c001.z + wc * c010.z + wd * c011.z
               + we * c100.z + wf * c101.z + wg * c110.z + wh * c111.z;
            bv = wa * c000.w + wb * c001.w + wc * c010.w + wd * c011.w
               + we * c100.w + wf * c101.w + wg * c110.w + wh * c111.w;
        } else {
            int i000 = base,               i001 = base + 1;
            int i010 = base + kG,          i011 = base + kG + 1;
            int i100 = base + kG * kG,     i101 = base + kG * kG + 1;
            int i110 = base + kG * kG + kG, i111 = base + kG * kG + kG + 1;
            sv = wa * sgrid[i000] + wb * sgrid[i001] + wc * sgrid[i010] + wd * sgrid[i011]
               + we * sgrid[i100] + wf * sgrid[i101] + wg * sgrid[i110] + wh * sgrid[i111];
            rv = wa * cgrid[3 * i000 + 0] + wb * cgrid[3 * i001 + 0]
               + wc * cgrid[3 * i010 + 0] + wd * cgrid[3 * i011 + 0]
               + we * cgrid[3 * i100 + 0] + wf * cgrid[3 * i101 + 0]
               + wg * cgrid[3 * i110 + 0] + wh * cgrid[3 * i111 + 0];
            gv = wa * cgrid[3 * i000 + 1] + wb * cgrid[3 * i001 + 1]
               + wc * cgrid[3 * i010 + 1] + wd * cgrid[3 * i011 + 1]
               + we * cgrid[3 * i100 + 1] + wf * cgrid[3 * i101 + 1]
               + wg * cgrid[3 * i110 + 1] + wh * cgrid[3 * i111 + 1];
            bv = wa * cgrid[3 * i000 + 2] + wb * cgrid[3 * i001 + 2]
               + wc * cgrid[3 * i010 + 2] + wd * cgrid[3 * i011 + 2]
               + we * cgrid[3 * i100 + 2] + wf * cgrid[3 * i101 + 2]
               + wg * cgrid[3 * i110 + 2] + wh * cgrid[3 * i111 + 2];
        }

        float sig = (sv > kDenTh) ? sv : 0.0f;
        float alpha = 1.0f - __expf(-sig * dt);
        float w = alpha * T;
        T *= (1.0f - alpha);
        wsum += w;
        accr = fmaf(w, rv, accr);
        accg = fmaf(w, gv, accg);
        accb = fmaf(w, bv, accb);
        if (T <= kTTh) break;   // exact: reference zeroes alpha once T <= thresh
    }

    float br = bg[0], bgc = bg[1], bb = bg[2];
    float omw = 1.0f - wsum;
    out[3 * i + 0] = fminf(fmaxf(fmaf(omw, br,  accr), 0.0f), 1.0f);
    out[3 * i + 1] = fminf(fmaxf(fmaf(omw, bgc, accg), 0.0f), 1.0f);
    out[3 * i + 2] = fminf(fmaxf(fmaf(omw, bb,  accb), 0.0f), 1.0f);
}

extern "C" void kernel_launch(void* const* d_in, const int* in_sizes, int n_in,
                              void* d_out, int out_size, void* d_ws, size_t ws_size,
                              hipStream_t stream)
{
    const float* rays_o = (const float*)d_in[0];
    const float* rays_d = (const float*)d_in[1];
    const float* sgrid  = (const float*)d_in[2];
    const float* cgrid  = (const float*)d_in[3];
    const float* bg     = (const float*)d_in[4];
    float* out = (float*)d_out;

    const size_t need = (size_t)kG3 * sizeof(float4);
    if (ws_size >= need) {
        float4* g4 = (float4*)d_ws;
        repack_k<<<(kG3 + 255) / 256, 256, 0, stream>>>(sgrid, cgrid, g4);
        render_k<1><<<(kNRays + 255) / 256, 256, 0, stream>>>(
            rays_o, rays_d, g4, nullptr, nullptr, bg, out);
    } else {
        render_k<0><<<(kNRays + 255) / 256, 256, 0, stream>>>(
            rays_o, rays_d, nullptr, sgrid, cgrid, bg, out);
    }
}

// Round 2
// 550.270 us; speedup vs baseline: 1.6935x; 1.6935x over previous
//
#include <hip/hip_runtime.h>
#include <hip/hip_fp16.h>

// NeRF ray-marching renderer, MI355X — round 2.
// Changes vs round 1:
//  - Grid repacked to half4 (sig,r,g,b) = 8 B/voxel -> z-corner PAIR is one
//    16B dwordx4 load: 4 gather instructions/step instead of 8, half the bytes.
//  - Ray coherence: counting-sort rays by quantized direction (128x128
//    buckets) so each wave's 64 rays march through nearby voxels ->
//    coalesced gathers + L1/L2 reuse. Output scattered to original order
//    (order-independent => deterministic).

constexpr int   kG     = 128;
constexpr int   kG3    = kG * kG * kG;
constexpr int   kSteps = 128;
constexpr int   kNRays = 262144;
constexpr int   kNB    = 128;              // direction bins per axis
constexpr int   kNBuckets = kNB * kNB;
constexpr float kBminX = -1.0f, kBminY = -0.5f, kBminZ = -1.0f;
constexpr float kBmaxX =  1.0f, kBmaxY =  0.5f, kBmaxZ =  1.0f;
constexpr float kMinNear = 0.05f;
constexpr float kDenTh   = 0.01f;
constexpr float kTTh     = 1e-4f;

__device__ inline unsigned pack2h(float a, float b) {
    return (unsigned)__half_as_ushort(__float2half_rn(a))
         | ((unsigned)__half_as_ushort(__float2half_rn(b)) << 16);
}
__device__ inline float2 up2h(unsigned u) {
    __half2 h = *reinterpret_cast<const __half2*>(&u);
    return __half22float2(h);
}

// ---- repack: sigma(f32) + rgb(f32x3) -> uint2 per voxel = (sig|r, g|b) halves
__global__ __launch_bounds__(256) void repack_half_k(
    const float* __restrict__ sig, const float* __restrict__ rgb,
    uint2* __restrict__ out)
{
    int i = blockIdx.x * 256 + threadIdx.x;
    if (i >= kG3) return;
    out[i] = make_uint2(pack2h(sig[i], rgb[3 * i + 0]),
                        pack2h(rgb[3 * i + 1], rgb[3 * i + 2]));
}

// ---- sort pipeline -------------------------------------------------------
__global__ __launch_bounds__(256) void zero_hist_k(int* __restrict__ hist)
{
    int i = blockIdx.x * 256 + threadIdx.x;
    if (i < kNBuckets) hist[i] = 0;
}

__global__ __launch_bounds__(256) void key_hist_k(
    const float* __restrict__ rays_d, int* __restrict__ keys,
    int* __restrict__ hist)
{
    int i = blockIdx.x * 256 + threadIdx.x;
    if (i >= kNRays) return;
    float dx = rays_d[3 * i + 0], dy = rays_d[3 * i + 1];
    // |dx|<~0.75, |dy|<~0.6 -> spread across bins with 0.625 scale
    int qx = (int)((dx * 0.625f + 0.5f) * (float)kNB);
    int qy = (int)((dy * 0.625f + 0.5f) * (float)kNB);
    qx = min(kNB - 1, max(0, qx));
    qy = min(kNB - 1, max(0, qy));
    int key = qx * kNB + qy;
    keys[i] = key;
    atomicAdd(&hist[key], 1);
}

// exclusive scan of 16384 ints, single block of 256 threads
__global__ __launch_bounds__(256) void scan_k(
    const int* __restrict__ hist, int* __restrict__ base)
{
    __shared__ int part[256];
    int t = threadIdx.x;
    int s = 0;
    #pragma unroll 4
    for (int k = 0; k < kNBuckets / 256; ++k) s += hist[t * (kNBuckets / 256) + k];
    part[t] = s;
    __syncthreads();
    if (t == 0) {
        int run = 0;
        for (int k = 0; k < 256; ++k) { int v = part[k]; part[k] = run; run += v; }
    }
    __syncthreads();
    int run = part[t];
    for (int k = 0; k < kNBuckets / 256; ++k) {
        int idx = t * (kNBuckets / 256) + k;
        base[idx] = run;
        run += hist[idx];
    }
}

__global__ __launch_bounds__(256) void scatter_k(
    const int* __restrict__ keys, int* __restrict__ base,
    int* __restrict__ perm)
{
    int i = blockIdx.x * 256 + threadIdx.x;
    if (i >= kNRays) return;
    int pos = atomicAdd(&base[keys[i]], 1);
    perm[pos] = i;
}

// ---- main render ---------------------------------------------------------
__global__ __launch_bounds__(256) void render_sorted_k(
    const float* __restrict__ rays_o, const float* __restrict__ rays_d,
    const uint2* __restrict__ grid, const int* __restrict__ perm,
    const float* __restrict__ bg, float* __restrict__ out)
{
    int j = blockIdx.x * 256 + threadIdx.x;
    if (j >= kNRays) return;
    int ray = perm[j];

    float ox = rays_o[3 * ray + 0], oy = rays_o[3 * ray + 1], oz = rays_o[3 * ray + 2];
    float dx = rays_d[3 * ray + 0], dy = rays_d[3 * ray + 1], dz = rays_d[3 * ray + 2];

    float sdx = (fabsf(dx) < 1e-9f) ? 1e-9f : dx;
    float sdy = (fabsf(dy) < 1e-9f) ? 1e-9f : dy;
    float sdz = (fabsf(dz) < 1e-9f) ? 1e-9f : dz;
    float t1x = (kBminX - ox) / sdx, t2x = (kBmaxX - ox) / sdx;
    float t1y = (kBminY - oy) / sdy, t2y = (kBmaxY - oy) / sdy;
    float t1z = (kBminZ - oz) / sdz, t2z = (kBmaxZ - oz) / sdz;
    float near_ = fmaxf(fmaxf(fminf(t1x, t2x), fminf(t1y, t2y)), fminf(t1z, t2z));
    float far_  = fminf(fminf(fmaxf(t1x, t2x), fmaxf(t1y, t2y)), fmaxf(t1z, t2z));
    near_ = fmaxf(near_, kMinNear);
    far_  = fmaxf(far_, near_ + 1e-6f);
    float dt = (far_ - near_) * (1.0f / (float)kSteps);

    const float sxs = (float)(kG - 1) / (kBmaxX - kBminX);
    const float sys = (float)(kG - 1) / (kBmaxY - kBminY);
    const float szs = (float)(kG - 1) / (kBmaxZ - kBminZ);

    float T = 1.0f, wsum = 0.0f;
    float accr = 0.0f, accg = 0.0f, accb = 0.0f;

    for (int s = 0; s < kSteps; ++s) {
        float t  = fmaf((float)s + 0.5f, dt, near_);
        float px = fmaf(t, dx, ox);
        float py = fmaf(t, dy, oy);
        float pz = fmaf(t, dz, oz);

        float ux = fminf(fmaxf((px - kBminX) * sxs, 0.0f), (float)(kG - 1));
        float uy = fminf(fmaxf((py - kBminY) * sys, 0.0f), (float)(kG - 1));
        float uz = fminf(fmaxf((pz - kBminZ) * szs, 0.0f), (float)(kG - 1));
        float u0x = fminf(floorf(ux), (float)(kG - 2));
        float u0y = fminf(floorf(uy), (float)(kG - 2));
        float u0z = fminf(floorf(uz), (float)(kG - 2));
        float fx = ux - u0x, fy = uy - u0y, fz = uz - u0z;
        int ix = (int)u0x, iy = (int)u0y, iz = (int)u0z;
        int vox = (ix << 14) + (iy << 7) + iz;

        // 4 pair-loads: each dwordx4 = corners (iz, iz+1) of one (x,y) column
        uint4 pa = *reinterpret_cast<const uint4*>(grid + vox);                 // x0 y0
        uint4 pb = *reinterpret_cast<const uint4*>(grid + vox + kG);            // x0 y1
        uint4 pc = *reinterpret_cast<const uint4*>(grid + vox + kG * kG);       // x1 y0
        uint4 pd = *reinterpret_cast<const uint4*>(grid + vox + kG * kG + kG);  // x1 y1

        float w0x = 1.0f - fx, w0y = 1.0f - fy, w0z = 1.0f - fz;
        float wa = w0x * w0y * w0z, wb = w0x * w0y * fz;
        float wc = w0x * fy  * w0z, wd = w0x * fy  * fz;
        float we = fx  * w0y * w0z, wf = fx  * w0y * fz;
        float wg = fx  * fy  * w0z, wh = fx  * fy  * fz;

        float2 srA0 = up2h(pa.x), gbA0 = up2h(pa.y), srA1 = up2h(pa.z), gbA1 = up2h(pa.w);
        float2 srB0 = up2h(pb.x), gbB0 = up2h(pb.y), srB1 = up2h(pb.z), gbB1 = up2h(pb.w);
        float2 srC0 = up2h(pc.x), gbC0 = up2h(pc.y), srC1 = up2h(pc.z), gbC1 = up2h(pc.w);
        float2 srD0 = up2h(pd.x), gbD0 = up2h(pd.y), srD1 = up2h(pd.z), gbD1 = up2h(pd.w);

        float sv = wa * srA0.x + wb * srA1.x + wc * srB0.x + wd * srB1.x
                 + we * srC0.x + wf * srC1.x + wg * srD0.x + wh * srD1.x;
        float rv = wa * srA0.y + wb * srA1.y + wc * srB0.y + wd * srB1.y
                 + we * srC0.y + wf * srC1.y + wg * srD0.y + wh * srD1.y;
        float gv = wa * gbA0.x + wb * gbA1.x + wc * gbB0.x + wd * gbB1.x
                 + we * gbC0.x + wf * gbC1.x + wg * gbD0.x + wh * gbD1.x;
        float bv = wa * gbA0.y + wb * gbA1.y + wc * gbB0.y + wd * gbB1.y
                 + we * gbC0.y + wf * gbC1.y + wg * gbD0.y + wh * gbD1.y;

        float sig = (sv > kDenTh) ? sv : 0.0f;
        float alpha = 1.0f - __expf(-sig * dt);
        float w = alpha * T;
        T *= (1.0f - alpha);
        wsum += w;
        accr = fmaf(w, rv, accr);
        accg = fmaf(w, gv, accg);
        accb = fmaf(w, bv, accb);
        if (T <= kTTh) break;   // exact: matches reference's where(T>th) gating
    }

    float br = bg[0], bgc = bg[1], bb = bg[2];
    float omw = 1.0f - wsum;
    out[3 * ray + 0] = fminf(fmaxf(fmaf(omw, br,  accr), 0.0f), 1.0f);
    out[3 * ray + 1] = fminf(fmaxf(fmaf(omw, bgc, accg), 0.0f), 1.0f);
    out[3 * ray + 2] = fminf(fmaxf(fmaf(omw, bb,  accb), 0.0f), 1.0f);
}

// ---- fallback (no workspace): round-1 scalar f32 path --------------------
__global__ __launch_bounds__(256) void render_plain_k(
    const float* __restrict__ rays_o, const float* __restrict__ rays_d,
    const float* __restrict__ sgrid, const float* __restrict__ cgrid,
    const float* __restrict__ bg, float* __restrict__ out)
{
    int i = blockIdx.x * 256 + threadIdx.x;
    if (i >= kNRays) return;

    float ox = rays_o[3 * i + 0], oy = rays_o[3 * i + 1], oz = rays_o[3 * i + 2];
    float dx = rays_d[3 * i + 0], dy = rays_d[3 * i + 1], dz = rays_d[3 * i + 2];
    float sdx = (fabsf(dx) < 1e-9f) ? 1e-9f : dx;
    float sdy = (fabsf(dy) < 1e-9f) ? 1e-9f : dy;
    float sdz = (fabsf(dz) < 1e-9f) ? 1e-9f : dz;
    float t1x = (kBminX - ox) / sdx, t2x = (kBmaxX - ox) / sdx;
    float t1y = (kBminY - oy) / sdy, t2y = (kBmaxY - oy) / sdy;
    float t1z = (kBminZ - oz) / sdz, t2z = (kBmaxZ - oz) / sdz;
    float near_ = fmaxf(fmaxf(fminf(t1x, t2x), fminf(t1y, t2y)), fminf(t1z, t2z));
    float far_  = fminf(fminf(fmaxf(t1x, t2x), fmaxf(t1y, t2y)), fmaxf(t1z, t2z));
    near_ = fmaxf(near_, kMinNear);
    far_  = fmaxf(far_, near_ + 1e-6f);
    float dt = (far_ - near_) * (1.0f / (float)kSteps);
    const float sxs = (float)(kG - 1) / (kBmaxX - kBminX);
    const float sys = (float)(kG - 1) / (kBmaxY - kBminY);
    const float szs = (float)(kG - 1) / (kBmaxZ - kBminZ);
    float T = 1.0f, wsum = 0.0f, accr = 0.0f, accg = 0.0f, accb = 0.0f;
    for (int s = 0; s < kSteps; ++s) {
        float t  = fmaf((float)s + 0.5f, dt, near_);
        float px = fmaf(t, dx, ox), py = fmaf(t, dy, oy), pz = fmaf(t, dz, oz);
        float ux = fminf(fmaxf((px - kBminX) * sxs, 0.0f), (float)(kG - 1));
        float uy = fminf(fmaxf((py - kBminY) * sys, 0.0f), (float)(kG - 1));
        float uz = fminf(fmaxf((pz - kBminZ) * szs, 0.0f), (float)(kG - 1));
        float u0x = fminf(floorf(ux), (float)(kG - 2));
        float u0y = fminf(floorf(uy), (float)(kG - 2));
        float u0z = fminf(floorf(uz), (float)(kG - 2));
        float fx = ux - u0x, fy = uy - u0y, fz = uz - u0z;
        int ix = (int)u0x, iy = (int)u0y, iz = (int)u0z;
        int base = (ix << 14) + (iy << 7) + iz;
        float w0x = 1.0f - fx, w0y = 1.0f - fy, w0z = 1.0f - fz;
        float wa = w0x * w0y * w0z, wb = w0x * w0y * fz;
        float wc = w0x * fy  * w0z, wd = w0x * fy  * fz;
        float we = fx  * w0y * w0z, wf = fx  * w0y * fz;
        float wg = fx  * fy  * w0z, wh = fx  * fy  * fz;
        int i000 = base, i001 = base + 1, i010 = base + kG, i011 = base + kG + 1;
        int i100 = base + kG * kG, i101 = i100 + 1, i110 = i100 + kG, i111 = i110 + 1;
        float sv = wa * sgrid[i000] + wb * sgrid[i001] + wc * sgrid[i010] + wd * sgrid[i011]
                 + we * sgrid[i100] + wf * sgrid[i101] + wg * sgrid[i110] + wh * sgrid[i111];
        float rv = wa * cgrid[3*i000+0] + wb * cgrid[3*i001+0] + wc * cgrid[3*i010+0] + wd * cgrid[3*i011+0]
                 + we * cgrid[3*i100+0] + wf * cgrid[3*i101+0] + wg * cgrid[3*i110+0] + wh * cgrid[3*i111+0];
        float gv = wa * cgrid[3*i000+1] + wb * cgrid[3*i001+1] + wc * cgrid[3*i010+1] + wd * cgrid[3*i011+1]
                 + we * cgrid[3*i100+1] + wf * cgrid[3*i101+1] + wg * cgrid[3*i110+1] + wh * cgrid[3*i111+1];
        float bv = wa * cgrid[3*i000+2] + wb * cgrid[3*i001+2] + wc * cgrid[3*i010+2] + wd * cgrid[3*i011+2]
                 + we * cgrid[3*i100+2] + wf * cgrid[3*i101+2] + wg * cgrid[3*i110+2] + wh * cgrid[3*i111+2];
        float sig = (sv > kDenTh) ? sv : 0.0f;
        float alpha = 1.0f - __expf(-sig * dt);
        float w = alpha * T;
        T *= (1.0f - alpha);
        wsum += w;
        accr = fmaf(w, rv, accr); accg = fmaf(w, gv, accg); accb = fmaf(w, bv, accb);
        if (T <= kTTh) break;
    }
    float br = bg[0], bgc = bg[1], bb = bg[2];
    float omw = 1.0f - wsum;
    out[3 * i + 0] = fminf(fmaxf(fmaf(omw, br,  accr), 0.0f), 1.0f);
    out[3 * i + 1] = fminf(fmaxf(fmaf(omw, bgc, accg), 0.0f), 1.0f);
    out[3 * i + 2] = fminf(fmaxf(fmaf(omw, bb,  accb), 0.0f), 1.0f);
}

extern "C" void kernel_launch(void* const* d_in, const int* in_sizes, int n_in,
                              void* d_out, int out_size, void* d_ws, size_t ws_size,
                              hipStream_t stream)
{
    const float* rays_o = (const float*)d_in[0];
    const float* rays_d = (const float*)d_in[1];
    const float* sgrid  = (const float*)d_in[2];
    const float* cgrid  = (const float*)d_in[3];
    const float* bg     = (const float*)d_in[4];
    float* out = (float*)d_out;

    // ws layout: half-grid | hist | base | keys | perm
    size_t off_grid = 0;
    size_t off_hist = off_grid + (size_t)kG3 * sizeof(uint2);          // 16 MB
    size_t off_base = off_hist + (size_t)kNBuckets * sizeof(int);      // +64 KB
    size_t off_keys = off_base + (size_t)kNBuckets * sizeof(int);      // +64 KB
    size_t off_perm = off_keys + (size_t)kNRays * sizeof(int);         // +1 MB
    size_t need     = off_perm + (size_t)kNRays * sizeof(int);         // +1 MB

    if (ws_size >= need) {
        char* ws = (char*)d_ws;
        uint2* grid  = (uint2*)(ws + off_grid);
        int* hist    = (int*)(ws + off_hist);
        int* bbase   = (int*)(ws + off_base);
        int* keys    = (int*)(ws + off_keys);
        int* perm    = (int*)(ws + off_perm);

        repack_half_k<<<(kG3 + 255) / 256, 256, 0, stream>>>(sgrid, cgrid, grid);
        zero_hist_k<<<(kNBuckets + 255) / 256, 256, 0, stream>>>(hist);
        key_hist_k<<<(kNRays + 255) / 256, 256, 0, stream>>>(rays_d, keys, hist);
        scan_k<<<1, 256, 0, stream>>>(hist, bbase);
        scatter_k<<<(kNRays + 255) / 256, 256, 0, stream>>>(keys, bbase, perm);
        render_sorted_k<<<(kNRays + 255) / 256, 256, 0, stream>>>(
            rays_o, rays_d, grid, perm, bg, out);
    } else {
        render_plain_k<<<(kNRays + 255) / 256, 256, 0, stream>>>(
            rays_o, rays_d, sgrid, cgrid, bg, out);
    }
}

// Round 3
// 372.968 us; speedup vs baseline: 2.4985x; 1.4754x over previous
//
#include <hip/hip_runtime.h>
#include <hip/hip_fp16.h>

// NeRF ray-marching renderer, MI355X — round 3.
//  - u8 quad-cell grid: cell(x,y,z) = uint4 (16B aligned) = 4 voxels
//    {(y,z),(y,z+1),(y+1,z),(y+1,z+1)} each packed u8x4 (sig,r,g,b).
//    -> trilerp = TWO dwordx4 gathers per step (x0,x1) instead of four.
//  - 2-segment ray split (compositing is associative) -> 2x waves.
//  - software prefetch of next step's 2 loads (no data-dependent break).
//  - direction counting-sort kept from round 2.

constexpr int   kG     = 128;
constexpr int   kG3    = kG * kG * kG;
constexpr int   kSteps = 128;
constexpr int   kNRays = 262144;
constexpr int   kNB    = 128;
constexpr int   kNBuckets = kNB * kNB;
constexpr float kBminX = -1.0f, kBminY = -0.5f, kBminZ = -1.0f;
constexpr float kBmaxX =  1.0f, kBmaxY =  0.5f, kBmaxZ =  1.0f;
constexpr float kSx = 63.5f, kSy = 127.0f, kSz = 63.5f;   // (G-1)/extent
constexpr float kMinNear = 0.05f;
constexpr float kTTh     = 1e-4f;

// ---------------- repack: quad u8 cells ----------------------------------
__device__ __forceinline__ unsigned packv(const float* __restrict__ sig,
                                          const float* __restrict__ rgb, int idx)
{
    unsigned s = (unsigned)__float2int_rn(fminf(fmaxf(sig[idx], 0.f), 1.f) * 255.f);
    unsigned r = (unsigned)__float2int_rn(fminf(fmaxf(rgb[3*idx+0], 0.f), 1.f) * 255.f);
    unsigned g = (unsigned)__float2int_rn(fminf(fmaxf(rgb[3*idx+1], 0.f), 1.f) * 255.f);
    unsigned b = (unsigned)__float2int_rn(fminf(fmaxf(rgb[3*idx+2], 0.f), 1.f) * 255.f);
    return s | (r << 8) | (g << 16) | (b << 24);
}

__global__ __launch_bounds__(256) void repack_quad_k(
    const float* __restrict__ sig, const float* __restrict__ rgb,
    uint4* __restrict__ out)
{
    int i = blockIdx.x * 256 + threadIdx.x;
    if (i >= kG3) return;
    int iz = i & 127, iy = (i >> 7) & 127, ix = i >> 14;
    int z1 = min(iz + 1, 127), y1 = min(iy + 1, 127);
    int b00 = (ix << 14) + (iy << 7) + iz;
    int b01 = (ix << 14) + (iy << 7) + z1;
    int b10 = (ix << 14) + (y1 << 7) + iz;
    int b11 = (ix << 14) + (y1 << 7) + z1;
    out[i] = make_uint4(packv(sig, rgb, b00), packv(sig, rgb, b01),
                        packv(sig, rgb, b10), packv(sig, rgb, b11));
}

// ---------------- sort pipeline (unchanged) -------------------------------
__global__ __launch_bounds__(256) void zero_hist_k(int* __restrict__ hist)
{
    int i = blockIdx.x * 256 + threadIdx.x;
    if (i < kNBuckets) hist[i] = 0;
}

__global__ __launch_bounds__(256) void key_hist_k(
    const float* __restrict__ rays_d, int* __restrict__ keys,
    int* __restrict__ hist)
{
    int i = blockIdx.x * 256 + threadIdx.x;
    if (i >= kNRays) return;
    float dx = rays_d[3 * i + 0], dy = rays_d[3 * i + 1];
    int qx = (int)((dx * 0.625f + 0.5f) * (float)kNB);
    int qy = (int)((dy * 0.625f + 0.5f) * (float)kNB);
    qx = min(kNB - 1, max(0, qx));
    qy = min(kNB - 1, max(0, qy));
    int key = qx * kNB + qy;
    keys[i] = key;
    atomicAdd(&hist[key], 1);
}

__global__ __launch_bounds__(256) void scan_k(
    const int* __restrict__ hist, int* __restrict__ base)
{
    __shared__ int part[256];
    int t = threadIdx.x;
    int s = 0;
    for (int k = 0; k < kNBuckets / 256; ++k) s += hist[t * (kNBuckets / 256) + k];
    part[t] = s;
    __syncthreads();
    if (t == 0) {
        int run = 0;
        for (int k = 0; k < 256; ++k) { int v = part[k]; part[k] = run; run += v; }
    }
    __syncthreads();
    int run = part[t];
    for (int k = 0; k < kNBuckets / 256; ++k) {
        int idx = t * (kNBuckets / 256) + k;
        base[idx] = run;
        run += hist[idx];
    }
}

__global__ __launch_bounds__(256) void scatter_k(
    const int* __restrict__ keys, int* __restrict__ base,
    int* __restrict__ perm)
{
    int i = blockIdx.x * 256 + threadIdx.x;
    if (i >= kNRays) return;
    int pos = atomicAdd(&base[keys[i]], 1);
    perm[pos] = i;
}

// ---------------- main render (quad cells, split, prefetch) ---------------
__device__ __forceinline__ void stepAddr(
    float near_, float dt, float ox, float oy, float oz,
    float dx, float dy, float dz, int s,
    int& cell, float& fx, float& fy, float& fz)
{
    float t  = fmaf((float)s + 0.5f, dt, near_);
    float px = fmaf(t, dx, ox), py = fmaf(t, dy, oy), pz = fmaf(t, dz, oz);
    float ux = fminf(fmaxf((px - kBminX) * kSx, 0.0f), 127.0f);
    float uy = fminf(fmaxf((py - kBminY) * kSy, 0.0f), 127.0f);
    float uz = fminf(fmaxf((pz - kBminZ) * kSz, 0.0f), 127.0f);
    float u0x = fminf(floorf(ux), 126.0f);
    float u0y = fminf(floorf(uy), 126.0f);
    float u0z = fminf(floorf(uz), 126.0f);
    fx = ux - u0x; fy = uy - u0y; fz = uz - u0z;
    cell = ((int)u0x << 14) + ((int)u0y << 7) + (int)u0z;
}

#define UB0(u) ((float)((u) & 0xffu))
#define UB1(u) ((float)(((u) >> 8) & 0xffu))
#define UB2(u) ((float)(((u) >> 16) & 0xffu))
#define UB3(u) ((float)((u) >> 24))

// SPLIT = 2: threads [0,N) do steps [0,64), [N,2N) do [64,128).
// SPLIT = 1: threads [0,N) do all 128 steps.
template <int SPLIT>
__global__ __launch_bounds__(256, 8) void render_q_k(
    const float* __restrict__ rays_o, const float* __restrict__ rays_d,
    const uint4* __restrict__ grid, const int* __restrict__ perm,
    float4* __restrict__ pRGBW, float* __restrict__ pT)
{
    int j = blockIdx.x * 256 + threadIdx.x;
    if (j >= kNRays * SPLIT) return;
    int seg = (SPLIT == 2 && j >= kNRays) ? 1 : 0;
    int sj  = j - seg * kNRays;
    int ray = perm[sj];

    float ox = rays_o[3 * ray + 0], oy = rays_o[3 * ray + 1], oz = rays_o[3 * ray + 2];
    float dx = rays_d[3 * ray + 0], dy = rays_d[3 * ray + 1], dz = rays_d[3 * ray + 2];

    float sdx = (fabsf(dx) < 1e-9f) ? 1e-9f : dx;
    float sdy = (fabsf(dy) < 1e-9f) ? 1e-9f : dy;
    float sdz = (fabsf(dz) < 1e-9f) ? 1e-9f : dz;
    float t1x = (kBminX - ox) / sdx, t2x = (kBmaxX - ox) / sdx;
    float t1y = (kBminY - oy) / sdy, t2y = (kBmaxY - oy) / sdy;
    float t1z = (kBminZ - oz) / sdz, t2z = (kBmaxZ - oz) / sdz;
    float near_ = fmaxf(fmaxf(fminf(t1x, t2x), fminf(t1y, t2y)), fminf(t1z, t2z));
    float far_  = fminf(fminf(fmaxf(t1x, t2x), fmaxf(t1y, t2y)), fmaxf(t1z, t2z));
    near_ = fmaxf(near_, kMinNear);
    far_  = fmaxf(far_, near_ + 1e-6f);
    float dt  = (far_ - near_) * (1.0f / (float)kSteps);
    float dtq = dt * (1.0f / 255.0f);

    const int nsteps = kSteps / SPLIT;
    const int s0     = seg * nsteps;

    int   c;  float fx, fy, fz;
    stepAddr(near_, dt, ox, oy, oz, dx, dy, dz, s0, c, fx, fy, fz);
    uint4 q0 = grid[c];
    uint4 q1 = grid[c + (1 << 14)];

    float T = 1.0f, wsum = 0.0f, ar = 0.0f, ag = 0.0f, ab = 0.0f;

    for (int s = 0; s < nsteps; ++s) {
        // prefetch step s+1 (clamped; loads in flight while we do math)
        int   cn; float nfx, nfy, nfz;
        int   sn = s0 + min(s + 1, nsteps - 1);
        stepAddr(near_, dt, ox, oy, oz, dx, dy, dz, sn, cn, nfx, nfy, nfz);
        uint4 m0 = grid[cn];
        uint4 m1 = grid[cn + (1 << 14)];

        float wz0 = 1.0f - fz, wy0 = 1.0f - fy;
        float w00 = wy0 * wz0, w01 = wy0 * fz, w10 = fy * wz0, w11 = fy * fz;

        float sA = w00 * UB0(q0.x) + w01 * UB0(q0.y) + w10 * UB0(q0.z) + w11 * UB0(q0.w);
        float sB = w00 * UB0(q1.x) + w01 * UB0(q1.y) + w10 * UB0(q1.z) + w11 * UB0(q1.w);
        float rA = w00 * UB1(q0.x) + w01 * UB1(q0.y) + w10 * UB1(q0.z) + w11 * UB1(q0.w);
        float rB = w00 * UB1(q1.x) + w01 * UB1(q1.y) + w10 * UB1(q1.z) + w11 * UB1(q1.w);
        float gA = w00 * UB2(q0.x) + w01 * UB2(q0.y) + w10 * UB2(q0.z) + w11 * UB2(q0.w);
        float gB = w00 * UB2(q1.x) + w01 * UB2(q1.y) + w10 * UB2(q1.z) + w11 * UB2(q1.w);
        float bA = w00 * UB3(q0.x) + w01 * UB3(q0.y) + w10 * UB3(q0.z) + w11 * UB3(q0.w);
        float bB = w00 * UB3(q1.x) + w01 * UB3(q1.y) + w10 * UB3(q1.z) + w11 * UB3(q1.w);

        float sv = fmaf(fx, sB - sA, sA);      // raw counts in [0,255]
        float rv = fmaf(fx, rB - rA, rA);
        float gv = fmaf(fx, gB - gA, gA);
        float bv = fmaf(fx, bB - bA, bA);

        float sigr  = (sv > 2.55f) ? sv : 0.0f;            // sigma > 0.01
        float alpha = 1.0f - __expf(-sigr * dtq);
        alpha = (T > kTTh) ? alpha : 0.0f;                  // reference gating
        float w = alpha * T;
        T *= (1.0f - alpha);
        wsum += w;
        ar = fmaf(w, rv, ar);
        ag = fmaf(w, gv, ag);
        ab = fmaf(w, bv, ab);

        q0 = m0; q1 = m1; fx = nfx; fy = nfy; fz = nfz;
    }

    pRGBW[j] = make_float4(ar, ag, ab, wsum);
    if (SPLIT == 2 && seg == 0) pT[sj] = T;
}

// ---------------- merge ---------------------------------------------------
template <int SPLIT>
__global__ __launch_bounds__(256) void merge_k(
    const float4* __restrict__ pRGBW, const float* __restrict__ pT,
    const int* __restrict__ perm, const float* __restrict__ bg,
    float* __restrict__ out)
{
    int k = blockIdx.x * 256 + threadIdx.x;
    if (k >= kNRays) return;
    float4 a = pRGBW[k];
    float ar = a.x, ag = a.y, ab = a.z, ws = a.w;
    if (SPLIT == 2) {
        float  T0 = pT[k];
        float4 b  = pRGBW[k + kNRays];
        ar = fmaf(T0, b.x, ar); ag = fmaf(T0, b.y, ag);
        ab = fmaf(T0, b.z, ab); ws = fmaf(T0, b.w, ws);
    }
    const float inv = 1.0f / 255.0f;
    ar *= inv; ag *= inv; ab *= inv;
    int   ray = perm[k];
    float omw = 1.0f - ws;
    out[3 * ray + 0] = fminf(fmaxf(fmaf(omw, bg[0], ar), 0.0f), 1.0f);
    out[3 * ray + 1] = fminf(fmaxf(fmaf(omw, bg[1], ag), 0.0f), 1.0f);
    out[3 * ray + 2] = fminf(fmaxf(fmaf(omw, bg[2], ab), 0.0f), 1.0f);
}

// ---------------- Tier B: round-2 f16 z-pair path -------------------------
__device__ inline unsigned pack2h(float a, float b) {
    return (unsigned)__half_as_ushort(__float2half_rn(a))
         | ((unsigned)__half_as_ushort(__float2half_rn(b)) << 16);
}
__device__ inline float2 up2h(unsigned u) {
    __half2 h = *reinterpret_cast<const __half2*>(&u);
    return __half22float2(h);
}

__global__ __launch_bounds__(256) void repack_half_k(
    const float* __restrict__ sig, const float* __restrict__ rgb,
    uint2* __restrict__ out)
{
    int i = blockIdx.x * 256 + threadIdx.x;
    if (i >= kG3) return;
    out[i] = make_uint2(pack2h(sig[i], rgb[3 * i + 0]),
                        pack2h(rgb[3 * i + 1], rgb[3 * i + 2]));
}

__global__ __launch_bounds__(256) void render_sorted_k(
    const float* __restrict__ rays_o, const float* __restrict__ rays_d,
    const uint2* __restrict__ grid, const int* __restrict__ perm,
    const float* __restrict__ bg, float* __restrict__ out)
{
    int j = blockIdx.x * 256 + threadIdx.x;
    if (j >= kNRays) return;
    int ray = perm[j];
    float ox = rays_o[3 * ray + 0], oy = rays_o[3 * ray + 1], oz = rays_o[3 * ray + 2];
    float dx = rays_d[3 * ray + 0], dy = rays_d[3 * ray + 1], dz = rays_d[3 * ray + 2];
    float sdx = (fabsf(dx) < 1e-9f) ? 1e-9f : dx;
    float sdy = (fabsf(dy) < 1e-9f) ? 1e-9f : dy;
    float sdz = (fabsf(dz) < 1e-9f) ? 1e-9f : dz;
    float t1x = (kBminX - ox) / sdx, t2x = (kBmaxX - ox) / sdx;
    float t1y = (kBminY - oy) / sdy, t2y = (kBmaxY - oy) / sdy;
    float t1z = (kBminZ - oz) / sdz, t2z = (kBmaxZ - oz) / sdz;
    float near_ = fmaxf(fmaxf(fminf(t1x, t2x), fminf(t1y, t2y)), fminf(t1z, t2z));
    float far_  = fminf(fminf(fmaxf(t1x, t2x), fmaxf(t1y, t2y)), fmaxf(t1z, t2z));
    near_ = fmaxf(near_, kMinNear);
    far_  = fmaxf(far_, near_ + 1e-6f);
    float dt = (far_ - near_) * (1.0f / (float)kSteps);
    float T = 1.0f, wsum = 0.0f, accr = 0.0f, accg = 0.0f, accb = 0.0f;
    for (int s = 0; s < kSteps; ++s) {
        int c; float fx, fy, fz;
        stepAddr(near_, dt, ox, oy, oz, dx, dy, dz, s, c, fx, fy, fz);
        uint4 pa = *reinterpret_cast<const uint4*>(grid + c);
        uint4 pb = *reinterpret_cast<const uint4*>(grid + c + kG);
        uint4 pc = *reinterpret_cast<const uint4*>(grid + c + kG * kG);
        uint4 pd = *reinterpret_cast<const uint4*>(grid + c + kG * kG + kG);
        float w0x = 1.0f - fx, w0y = 1.0f - fy, w0z = 1.0f - fz;
        float wa = w0x * w0y * w0z, wb = w0x * w0y * fz;
        float wc = w0x * fy * w0z,  wd = w0x * fy * fz;
        float we = fx * w0y * w0z,  wf = fx * w0y * fz;
        float wg = fx * fy * w0z,   wh = fx * fy * fz;
        float2 srA0 = up2h(pa.x), gbA0 = up2h(pa.y), srA1 = up2h(pa.z), gbA1 = up2h(pa.w);
        float2 srB0 = up2h(pb.x), gbB0 = up2h(pb.y), srB1 = up2h(pb.z), gbB1 = up2h(pb.w);
        float2 srC0 = up2h(pc.x), gbC0 = up2h(pc.y), srC1 = up2h(pc.z), gbC1 = up2h(pc.w);
        float2 srD0 = up2h(pd.x), gbD0 = up2h(pd.y), srD1 = up2h(pd.z), gbD1 = up2h(pd.w);
        float sv = wa*srA0.x + wb*srA1.x + wc*srB0.x + wd*srB1.x
                 + we*srC0.x + wf*srC1.x + wg*srD0.x + wh*srD1.x;
        float rv = wa*srA0.y + wb*srA1.y + wc*srB0.y + wd*srB1.y
                 + we*srC0.y + wf*srC1.y + wg*srD0.y + wh*srD1.y;
        float gv = wa*gbA0.x + wb*gbA1.x + wc*gbB0.x + wd*gbB1.x
                 + we*gbC0.x + wf*gbC1.x + wg*gbD0.x + wh*gbD1.x;
        float bv = wa*gbA0.y + wb*gbA1.y + wc*gbB0.y + wd*gbB1.y
                 + we*gbC0.y + wf*gbC1.y + wg*gbD0.y + wh*gbD1.y;
        float sig = (sv > 0.01f) ? sv : 0.0f;
        float alpha = 1.0f - __expf(-sig * dt);
        float w = alpha * T;
        T *= (1.0f - alpha);
        wsum += w;
        accr = fmaf(w, rv, accr); accg = fmaf(w, gv, accg); accb = fmaf(w, bv, accb);
        if (T <= kTTh) break;
    }
    float omw = 1.0f - wsum;
    out[3 * ray + 0] = fminf(fmaxf(fmaf(omw, bg[0], accr), 0.0f), 1.0f);
    out[3 * ray + 1] = fminf(fmaxf(fmaf(omw, bg[1], accg), 0.0f), 1.0f);
    out[3 * ray + 2] = fminf(fmaxf(fmaf(omw, bg[2], accb), 0.0f), 1.0f);
}

// ---------------- Tier C: plain fallback ----------------------------------
__global__ __launch_bounds__(256) void render_plain_k(
    const float* __restrict__ rays_o, const float* __restrict__ rays_d,
    const float* __restrict__ sgrid, const float* __restrict__ cgrid,
    const float* __restrict__ bg, float* __restrict__ out)
{
    int i = blockIdx.x * 256 + threadIdx.x;
    if (i >= kNRays) return;
    float ox = rays_o[3 * i + 0], oy = rays_o[3 * i + 1], oz = rays_o[3 * i + 2];
    float dx = rays_d[3 * i + 0], dy = rays_d[3 * i + 1], dz = rays_d[3 * i + 2];
    float sdx = (fabsf(dx) < 1e-9f) ? 1e-9f : dx;
    float sdy = (fabsf(dy) < 1e-9f) ? 1e-9f : dy;
    float sdz = (fabsf(dz) < 1e-9f) ? 1e-9f : dz;
    float t1x = (kBminX - ox) / sdx, t2x = (kBmaxX - ox) / sdx;
    float t1y = (kBminY - oy) / sdy, t2y = (kBmaxY - oy) / sdy;
    float t1z = (kBminZ - oz) / sdz, t2z = (kBmaxZ - oz) / sdz;
    float near_ = fmaxf(fmaxf(fminf(t1x, t2x), fminf(t1y, t2y)), fminf(t1z, t2z));
    float far_  = fminf(fminf(fmaxf(t1x, t2x), fmaxf(t1y, t2y)), fmaxf(t1z, t2z));
    near_ = fmaxf(near_, kMinNear);
    far_  = fmaxf(far_, near_ + 1e-6f);
    float dt = (far_ - near_) * (1.0f / (float)kSteps);
    float T = 1.0f, wsum = 0.0f, accr = 0.0f, accg = 0.0f, accb = 0.0f;
    for (int s = 0; s < kSteps; ++s) {
        int base; float fx, fy, fz;
        stepAddr(near_, dt, ox, oy, oz, dx, dy, dz, s, base, fx, fy, fz);
        float w0x = 1.0f - fx, w0y = 1.0f - fy, w0z = 1.0f - fz;
        float wa = w0x*w0y*w0z, wb = w0x*w0y*fz, wc = w0x*fy*w0z, wd = w0x*fy*fz;
        float we = fx*w0y*w0z,  wf = fx*w0y*fz,  wg = fx*fy*w0z,  wh = fx*fy*fz;
        int i000 = base, i001 = base + 1, i010 = base + kG, i011 = base + kG + 1;
        int i100 = base + kG*kG, i101 = i100 + 1, i110 = i100 + kG, i111 = i110 + 1;
        float sv = wa*sgrid[i000] + wb*sgrid[i001] + wc*sgrid[i010] + wd*sgrid[i011]
                 + we*sgrid[i100] + wf*sgrid[i101] + wg*sgrid[i110] + wh*sgrid[i111];
        float rv = wa*cgrid[3*i000+0] + wb*cgrid[3*i001+0] + wc*cgrid[3*i010+0] + wd*cgrid[3*i011+0]
                 + we*cgrid[3*i100+0] + wf*cgrid[3*i101+0] + wg*cgrid[3*i110+0] + wh*cgrid[3*i111+0];
        float gv = wa*cgrid[3*i000+1] + wb*cgrid[3*i001+1] + wc*cgrid[3*i010+1] + wd*cgrid[3*i011+1]
                 + we*cgrid[3*i100+1] + wf*cgrid[3*i101+1] + wg*cgrid[3*i110+1] + wh*cgrid[3*i111+1];
        float bv = wa*cgrid[3*i000+2] + wb*cgrid[3*i001+2] + wc*cgrid[3*i010+2] + wd*cgrid[3*i011+2]
                 + we*cgrid[3*i100+2] + wf*cgrid[3*i101+2] + wg*cgrid[3*i110+2] + wh*cgrid[3*i111+2];
        float sig = (sv > 0.01f) ? sv : 0.0f;
        float alpha = 1.0f - __expf(-sig * dt);
        float w = alpha * T;
        T *= (1.0f - alpha);
        wsum += w;
        accr = fmaf(w, rv, accr); accg = fmaf(w, gv, accg); accb = fmaf(w, bv, accb);
        if (T <= kTTh) break;
    }
    float omw = 1.0f - wsum;
    out[3 * i + 0] = fminf(fmaxf(fmaf(omw, bg[0], accr), 0.0f), 1.0f);
    out[3 * i + 1] = fminf(fmaxf(fmaf(omw, bg[1], accg), 0.0f), 1.0f);
    out[3 * i + 2] = fminf(fmaxf(fmaf(omw, bg[2], accb), 0.0f), 1.0f);
}

extern "C" void kernel_launch(void* const* d_in, const int* in_sizes, int n_in,
                              void* d_out, int out_size, void* d_ws, size_t ws_size,
                              hipStream_t stream)
{
    const float* rays_o = (const float*)d_in[0];
    const float* rays_d = (const float*)d_in[1];
    const float* sgrid  = (const float*)d_in[2];
    const float* cgrid  = (const float*)d_in[3];
    const float* bg     = (const float*)d_in[4];
    float* out = (float*)d_out;

    // Tier A layout: quad grid | hist | base | keys | perm | pRGBW | pT
    size_t off_grid = 0;
    size_t off_hist = off_grid + (size_t)kG3 * sizeof(uint4);          // 32 MB
    size_t off_base = off_hist + (size_t)kNBuckets * sizeof(int);
    size_t off_keys = off_base + (size_t)kNBuckets * sizeof(int);
    size_t off_perm = off_keys + (size_t)kNRays * sizeof(int);
    size_t off_rgbw = off_perm + (size_t)kNRays * sizeof(int);
    size_t off_pt   = off_rgbw + (size_t)(2 * kNRays) * sizeof(float4);
    size_t needA    = off_pt + (size_t)kNRays * sizeof(float);         // ~43.5 MB

    // Tier B layout: half grid | hist | base | keys | perm  (~18.3 MB)
    size_t b_grid = 0;
    size_t b_hist = b_grid + (size_t)kG3 * sizeof(uint2);
    size_t b_base = b_hist + (size_t)kNBuckets * sizeof(int);
    size_t b_keys = b_base + (size_t)kNBuckets * sizeof(int);
    size_t b_perm = b_keys + (size_t)kNRays * sizeof(int);
    size_t needB  = b_perm + (size_t)kNRays * sizeof(int);

    if (ws_size >= needA) {
        char* ws = (char*)d_ws;
        uint4*  grid  = (uint4*)(ws + off_grid);
        int*    hist  = (int*)(ws + off_hist);
        int*    bbase = (int*)(ws + off_base);
        int*    keys  = (int*)(ws + off_keys);
        int*    perm  = (int*)(ws + off_perm);
        float4* rgbw  = (float4*)(ws + off_rgbw);
        float*  pt    = (float*)(ws + off_pt);

        repack_quad_k<<<(kG3 + 255) / 256, 256, 0, stream>>>(sgrid, cgrid, grid);
        zero_hist_k<<<(kNBuckets + 255) / 256, 256, 0, stream>>>(hist);
        key_hist_k<<<(kNRays + 255) / 256, 256, 0, stream>>>(rays_d, keys, hist);
        scan_k<<<1, 256, 0, stream>>>(hist, bbase);
        scatter_k<<<(kNRays + 255) / 256, 256, 0, stream>>>(keys, bbase, perm);
        render_q_k<2><<<(2 * kNRays + 255) / 256, 256, 0, stream>>>(
            rays_o, rays_d, grid, perm, rgbw, pt);
        merge_k<2><<<(kNRays + 255) / 256, 256, 0, stream>>>(rgbw, pt, perm, bg, out);
    } else if (ws_size >= needB) {
        char* ws = (char*)d_ws;
        uint2* grid  = (uint2*)(ws + b_grid);
        int*   hist  = (int*)(ws + b_hist);
        int*   bbase = (int*)(ws + b_base);
        int*   keys  = (int*)(ws + b_keys);
        int*   perm  = (int*)(ws + b_perm);
        repack_half_k<<<(kG3 + 255) / 256, 256, 0, stream>>>(sgrid, cgrid, grid);
        zero_hist_k<<<(kNBuckets + 255) / 256, 256, 0, stream>>>(hist);
        key_hist_k<<<(kNRays + 255) / 256, 256, 0, stream>>>(rays_d, keys, hist);
        scan_k<<<1, 256, 0, stream>>>(hist, bbase);
        scatter_k<<<(kNRays + 255) / 256, 256, 0, stream>>>(keys, bbase, perm);
        render_sorted_k<<<(kNRays + 255) / 256, 256, 0, stream>>>(
            rays_o, rays_d, grid, perm, bg, out);
    } else {
        render_plain_k<<<(kNRays + 255) / 256, 256, 0, stream>>>(
            rays_o, rays_d, sgrid, cgrid, bg, out);
    }
}